// Round 4
// baseline (236.153 us; speedup 1.0000x reference)
//
#include <hip/hip_runtime.h>
#include <hip/hip_bf16.h>
#include <hip/hip_cooperative_groups.h>

namespace cg = cooperative_groups;

#define L 256
#define DH 512
#define BQ 2
#define NBLK 256
#define NTHR 512

typedef __attribute__((ext_vector_type(8))) short bf16x8;
typedef __attribute__((ext_vector_type(4))) float f32x4;

static __device__ __forceinline__ ushort f2b(float v) {
  __hip_bfloat16 h = __float2bfloat16(v);
  return *(ushort*)&h;
}

struct PARAMS {
  const float *x, *fcw, *fcb, *b1, *b2, *bl, *bf;
  float *out, *rep, *depf, *headf, *g1, *attn;
  ushort *xb, *repb, *attnb, *fcwt, *w1t, *w2t, *wf1t, *wf2t;
  const float *w1, *w2, *wf1, *wf2;
};

// 16x16 output tile, K=512, one wave. A,Bt both [16-row][K] bf16 K-major.
__device__ __forceinline__ void gemm16(const ushort* __restrict__ A,
                                       const ushort* __restrict__ Bt,
                                       int m0, int n0, f32x4& acc)
{
  const int l  = threadIdx.x & 63;
  const int fr = l & 15, kg = (l >> 4) << 3;
  const ushort* pa = A  + (size_t)(m0 + fr) * DH + kg;
  const ushort* pb = Bt + (size_t)(n0 + fr) * DH + kg;
#pragma unroll 8
  for (int kt = 0; kt < DH; kt += 32) {
    const bf16x8 a = *(const bf16x8*)(pa + kt);
    const bf16x8 b = *(const bf16x8*)(pb + kt);
    acc = __builtin_amdgcn_mfma_f32_16x16x32_bf16(a, b, acc, 0, 0, 0);
  }
}

__global__ __launch_bounds__(NTHR) void mega(PARAMS p)
{
  cg::grid_group grid = cg::this_grid();
  const int tid  = threadIdx.x;
  const int bid  = blockIdx.x;
  const int widx = tid >> 6;
  const int lane = tid & 63;

  // ---------- P0: cast x -> xb ; transpose+cast 5 weights to [N][K] bf16 ----------
  {
    const int gid = bid * NTHR + tid;
    if (gid < 65536) {                                  // 512*512/4 float4 groups
      const float4 v = ((const float4*)p.x)[gid];
      ushort4 o; o.x = f2b(v.x); o.y = f2b(v.y); o.z = f2b(v.z); o.w = f2b(v.w);
      ((ushort4*)p.xb)[gid] = o;
    }
    __shared__ float tr[32][33];
    const int tx = tid & 31, ty = tid >> 5;             // ty in [0,16)
    const int r0 = (bid >> 4) << 5, c0 = (bid & 15) << 5;
    const float* srcs[5] = {p.fcw, p.w1, p.w2, p.wf1, p.wf2};
    ushort*      dsts[5] = {p.fcwt, p.w1t, p.w2t, p.wf1t, p.wf2t};
#pragma unroll
    for (int s = 0; s < 5; ++s) {
      __syncthreads();
      tr[ty][tx]      = srcs[s][(size_t)(r0 + ty) * DH + c0 + tx];
      tr[ty + 16][tx] = srcs[s][(size_t)(r0 + ty + 16) * DH + c0 + tx];
      __syncthreads();
      dsts[s][(size_t)(c0 + ty) * DH + r0 + tx]      = f2b(tr[tx][ty]);
      dsts[s][(size_t)(c0 + ty + 16) * DH + r0 + tx] = f2b(tr[tx][ty + 16]);
    }
  }
  grid.sync();

  // ---------- P1: rep = elu(x @ fc_w + fc_b), fp32 + bf16 ----------
  {
    const int wv = widx * NBLK + bid;                   // 0..2047
    if (wv < 1024) {
      const int m0 = (wv >> 5) << 4, n0 = (wv & 31) << 4;
      f32x4 acc = {};
      gemm16(p.xb, p.fcwt, m0, n0, acc);
      const int fr = lane & 15, rg = (lane >> 4) << 2;
      const int col = n0 + fr;
      const float bv = p.fcb[col];
#pragma unroll
      for (int r = 0; r < 4; ++r) {
        float v = acc[r] + bv;
        v = v > 0.0f ? v : (__expf(v) - 1.0f);
        const size_t idx = (size_t)(m0 + rg + r) * DH + col;
        p.rep[idx] = v;
        p.repb[idx] = f2b(v);
      }
    }
  }
  grid.sync();

  // ---------- P2: depf = rep@w1+b1+bl ; headf = rep@w2+b2 ; g1 = rep@wf1 ----------
  {
    const int wv = widx * NBLK + bid;
    for (int tt = wv; tt < 3072; tt += 2048) {
      const int z = tt >> 10, rem = tt & 1023;
      const int m0 = (rem >> 5) << 4, n0 = (rem & 31) << 4;
      const ushort* Bt = (z == 0) ? p.w1t : (z == 1) ? p.w2t : p.wf1t;
      f32x4 acc = {};
      gemm16(p.repb, Bt, m0, n0, acc);
      const int fr = lane & 15, rg = (lane >> 4) << 2;
      const int col = n0 + fr;
#pragma unroll
      for (int r = 0; r < 4; ++r) {
        const size_t idx = (size_t)(m0 + rg + r) * DH + col;
        if (z == 0)      p.depf[idx]  = acc[r] + p.b1[col] + p.bl[col];
        else if (z == 1) p.headf[idx] = acc[r] + p.b2[col];
        else             p.g1[idx]    = acc[r];
      }
    }
  }
  grid.sync();

  // ---------- P3: balanced single-phase masked tanh-clip softmax attention ----------
  // block handles rows {pp, 127-pp, 128+pp, 255-pp} (const 510 active row-iters);
  // w = exp(C*tanh(s/C)) = exp2(A - B*rcp(exp2(s*c1)+1)); row 255 fully masked -> uniform.
  {
    if (bid < 2 * 64) {
      const int pp = bid & 63, b = bid >> 6;
      const int h = tid;
      const float c1 = 0.57707801635558534f;            // 2*log2(e)/C
      const float Ac = 7.2134752044448169f;             // C*log2(e)
      const float Bc = 14.426950408889634f;             // 2C*log2(e)
      int irow[4] = { pp, 127 - pp, 128 + pp, 255 - pp };
      float hb[4], sa[4] = {}, aa[4] = {};
#pragma unroll
      for (int r = 0; r < 4; ++r)
        hb[r] = p.headf[((size_t)b * L + irow[r]) * DH + h] * c1;
      const float* dp = p.depf + (size_t)b * L * DH + h;
      const float* rp = p.rep  + (size_t)b * L * DH + h;
      const int jstart = (pp == 0) ? 0 : (pp + 1);
      for (int j = jstart; j < L; ++j) {
        const float d  = dp[(size_t)j * DH];
        const float rv = rp[(size_t)j * DH];
#pragma unroll
        for (int r = 0; r < 4; ++r) {
          if (irow[r] == 255) {                         // uniform fully-masked row
            sa[r] += 1.0f; aa[r] += rv;
          } else if (j > irow[r]) {                     // block-uniform branch
            const float E = __builtin_amdgcn_exp2f(fmaf(d, c1, hb[r]));
            const float w = __builtin_amdgcn_exp2f(
                fmaf(-Bc, __builtin_amdgcn_rcpf(E + 1.0f), Ac));
            sa[r] += w;
            aa[r] = fmaf(w, rv, aa[r]);
          }
        }
      }
#pragma unroll
      for (int r = 0; r < 4; ++r) {
        const float v = aa[r] * __builtin_amdgcn_rcpf(sa[r]);
        const size_t o = ((size_t)b * L + irow[r]) * DH + h;
        p.attn[o] = v;
        p.attnb[o] = f2b(v);
      }
    }
  }
  grid.sync();

  // ---------- P4: g2 = attn@wf2 ; gate = sigmoid(g1+g2+bf) ; out = mix ----------
  {
    const int wv = widx * NBLK + bid;
    if (wv < 1024) {
      const int m0 = (wv >> 5) << 4, n0 = (wv & 31) << 4;
      f32x4 acc = {};
      gemm16(p.attnb, p.wf2t, m0, n0, acc);
      const int fr = lane & 15, rg = (lane >> 4) << 2;
      const int col = n0 + fr;
      const float bv = p.bf[col];
#pragma unroll
      for (int r = 0; r < 4; ++r) {
        const size_t idx = (size_t)(m0 + rg + r) * DH + col;
        const float s = p.g1[idx] + acc[r] + bv;
        const float gate = __builtin_amdgcn_rcpf(
            1.0f + __builtin_amdgcn_exp2f(-s * 1.4426950408889634f));
        p.out[idx] = gate * p.rep[idx] + (1.0f - gate) * p.attn[idx];
      }
    }
  }
}

extern "C" void kernel_launch(void* const* d_in, const int* in_sizes, int n_in,
                              void* d_out, int out_size, void* d_ws, size_t ws_size,
                              hipStream_t stream)
{
  PARAMS p;
  p.x   = (const float*)d_in[0];
  p.fcw = (const float*)d_in[1];
  p.fcb = (const float*)d_in[2];
  p.w1  = (const float*)d_in[3];
  p.b1  = (const float*)d_in[4];
  p.w2  = (const float*)d_in[5];
  p.b2  = (const float*)d_in[6];
  p.bl  = (const float*)d_in[7];
  p.wf1 = (const float*)d_in[8];
  p.wf2 = (const float*)d_in[9];
  p.bf  = (const float*)d_in[10];
  p.out = (float*)d_out;

  const size_t MAT = (size_t)BQ * L * DH;               // 262144
  float* ws = (float*)d_ws;
  p.rep   = ws;
  p.depf  = ws + 1 * MAT;
  p.headf = ws + 2 * MAT;
  p.g1    = ws + 3 * MAT;
  p.attn  = ws + 4 * MAT;
  ushort* ub = (ushort*)(ws + 5 * MAT);
  p.xb    = ub + 0 * MAT;
  p.repb  = ub + 1 * MAT;
  p.attnb = ub + 2 * MAT;
  p.fcwt  = ub + 3 * MAT;
  p.w1t   = ub + 4 * MAT;
  p.w2t   = ub + 5 * MAT;
  p.wf1t  = ub + 6 * MAT;
  p.wf2t  = ub + 7 * MAT;

  void* args[] = { &p };
  hipLaunchCooperativeKernel((void*)mega, dim3(NBLK), dim3(NTHR), args, 0, stream);
}